// Round 7
// baseline (239.295 us; speedup 1.0000x reference)
//
#include <hip/hip_runtime.h>
#include <stdint.h>

#define D_MODEL 1024
#define NHEAD 16
#define DKH 64
#define BATCH 4
#define SEQ 2048
#define M_ROWS (BATCH*SEQ)   // 8192
#define NBH (BATCH*NHEAD)    // 64

typedef float f32x4 __attribute__((ext_vector_type(4)));
typedef float f32x16 __attribute__((ext_vector_type(16)));
typedef __bf16 bf16x8 __attribute__((ext_vector_type(8)));
typedef __bf16 bf16x4v __attribute__((ext_vector_type(4)));
typedef short short4v __attribute__((ext_vector_type(4)));
typedef unsigned int uint2v __attribute__((ext_vector_type(2)));

__device__ __forceinline__ unsigned short f2bf(float x) {
    __bf16 b = (__bf16)x;                      // hardware v_cvt (RNE)
    return __builtin_bit_cast(unsigned short, b);
}

#define GLL(gsrc, ldst) \
    __builtin_amdgcn_global_load_lds((const __attribute__((address_space(1))) void*)(gsrc), \
                                     (__attribute__((address_space(3))) void*)(ldst), 16, 0, 0)

// ---------------------------------------------------------------------------
// Kernel 1: fp32 -> bf16 conversion / packing
// ---------------------------------------------------------------------------
__global__ __launch_bounds__(256) void k_convert(
    const float* __restrict__ z,  const float* __restrict__ wq,
    const float* __restrict__ wk, const float* __restrict__ wv,
    const float* __restrict__ wo,
    const float* __restrict__ bq, const float* __restrict__ bk,
    const float* __restrict__ bv,
    unsigned short* __restrict__ zb, unsigned short* __restrict__ wqkv,
    unsigned short* __restrict__ wob, float* __restrict__ biasf)
{
    int i = blockIdx.x * 256 + threadIdx.x;   // 0 .. 2097151
    {
        float4 v = ((const float4*)z)[i];
        ushort4 o; o.x = f2bf(v.x); o.y = f2bf(v.y); o.z = f2bf(v.z); o.w = f2bf(v.w);
        ((ushort4*)zb)[i] = o;
    }
    if (i < 262144) {   // 1048576/4 per weight matrix
        float4 v;
        ushort4 o;
        v = ((const float4*)wq)[i];
        o.x=f2bf(v.x); o.y=f2bf(v.y); o.z=f2bf(v.z); o.w=f2bf(v.w);
        ((ushort4*)wqkv)[i] = o;
        v = ((const float4*)wk)[i];
        o.x=f2bf(v.x); o.y=f2bf(v.y); o.z=f2bf(v.z); o.w=f2bf(v.w);
        ((ushort4*)wqkv)[262144 + i] = o;
        v = ((const float4*)wv)[i];
        o.x=f2bf(v.x); o.y=f2bf(v.y); o.z=f2bf(v.z); o.w=f2bf(v.w);
        ((ushort4*)wqkv)[524288 + i] = o;
        v = ((const float4*)wo)[i];
        o.x=f2bf(v.x); o.y=f2bf(v.y); o.z=f2bf(v.z); o.w=f2bf(v.w);
        ((ushort4*)wob)[i] = o;
    }
    if (i < 1024) {
        biasf[i]        = bq[i];
        biasf[1024 + i] = bk[i];
        biasf[2048 + i] = bv[i];
    }
}

// ---------------------------------------------------------------------------
// Kernel 2: QKV projection GEMM  C[8192,3072] = zb * wqkv^T + bias
// Q is pre-scaled by log2(e)/8 (softmax scale folded, log2 domain) so the
// attention kernel can use raw v_exp_f32 (2^x) with no per-element mul/sub.
// ---------------------------------------------------------------------------
__global__ __launch_bounds__(256) void k_gemm_qkv(
    const unsigned short* __restrict__ A,   // [8192][1024] bf16
    const unsigned short* __restrict__ Bw,  // [3072][1024] bf16
    const float* __restrict__ biasf,        // [3072]
    unsigned short* __restrict__ qb, unsigned short* __restrict__ kb,
    unsigned short* __restrict__ vtb)
{
    __shared__ unsigned short lds_a[128 * 32];
    __shared__ unsigned short lds_b[128 * 32];

    const int NT = 3072 / 128;  // 24
    int bid = blockIdx.x;
    int tn = bid % NT, tm = bid / NT;
    int m0 = tm * 128, n0 = tn * 128;
    int tid = threadIdx.x, wid = tid >> 6, lane = tid & 63;
    int wm = wid >> 1, wn = wid & 1;

    f32x4 acc[4][4] = {};

    int srow = lane >> 2;        // 0..15
    int scol = (lane & 3) * 8;   // element offset within 32-col row

    for (int kt = 0; kt < 32; ++kt) {
        int k0 = kt * 32;
#pragma unroll
        for (int i = 0; i < 2; ++i) {
            int rb = (wid * 2 + i) * 16;
            GLL(A  + (size_t)(m0 + rb + srow) * 1024 + k0 + scol, lds_a + rb * 32);
            GLL(Bw + (size_t)(n0 + rb + srow) * 1024 + k0 + scol, lds_b + rb * 32);
        }
        __syncthreads();
        bf16x8 af[4], bfr[4];
#pragma unroll
        for (int i = 0; i < 4; ++i)
            af[i] = *(const bf16x8*)(lds_a + (wm * 64 + i * 16 + (lane & 15)) * 32 + (lane >> 4) * 8);
#pragma unroll
        for (int j = 0; j < 4; ++j)
            bfr[j] = *(const bf16x8*)(lds_b + (wn * 64 + j * 16 + (lane & 15)) * 32 + (lane >> 4) * 8);
#pragma unroll
        for (int i = 0; i < 4; ++i)
#pragma unroll
            for (int j = 0; j < 4; ++j)
                acc[i][j] = __builtin_amdgcn_mfma_f32_16x16x32_bf16(af[i], bfr[j], acc[i][j], 0, 0, 0);
        __syncthreads();
    }

    const float QSC = 0.18033688011112042f;  // log2(e) / sqrt(64)
    int t = n0 >> 10;  // 0=Q 1=K 2=V
#pragma unroll
    for (int j = 0; j < 4; ++j) {
        int col = n0 + wn * 64 + j * 16 + (lane & 15);
        float bias = biasf[col];
        int d  = col & 1023;
        int h  = d >> 6;
        int dk = d & 63;
#pragma unroll
        for (int i = 0; i < 4; ++i) {
#pragma unroll
            for (int r = 0; r < 4; ++r) {
                int row = m0 + wm * 64 + i * 16 + (lane >> 4) * 4 + r;
                float v = acc[i][j][r] + bias;
                if (t == 0) v *= QSC;            // uniform per block
                unsigned short bv16 = f2bf(v);
                int b_ = row >> 11, s_ = row & 2047;
                int bh = b_ * NHEAD + h;
                if (t == 0)      qb[((size_t)bh * SEQ + s_) * DKH + dk] = bv16;
                else if (t == 1) kb[((size_t)bh * SEQ + s_) * DKH + dk] = bv16;
                else             vtb[((size_t)bh * DKH + dk) * SEQ + s_] = bv16;
            }
        }
    }
}

// ---------------------------------------------------------------------------
// Kernel 3: flash attention, 32x32 MFMA, no-max unnormalized softmax.
//   S^T = mfma_32x32x16(K, Qscaled): col = q (lane&31), row = kv.
//   P = exp2(S^T); B-frag of mfma_32x32x8bf16_1k for K=8 step ks is EXACTLY
//   C-regs [4ks..4ks+3] of the own lane (zero cross-lane, zero LDS repack).
//   PV: O^T += V^T @ P via 16x mfma_32x32x8 (2 d-tiles x 8 ks).
//   K and V both GLL-staged, double-buffered, 16B-chunk XOR swizzle
//   (all LDS read phases enumerate to <=2 lanes/bank = free).
// ---------------------------------------------------------------------------
__device__ __forceinline__ void stage_kv(
    const unsigned short* __restrict__ kb, const unsigned short* __restrict__ vtb,
    unsigned short* lk, unsigned short* lv,
    int bh, int t, int wid, int srow8, int sc)
{
#pragma unroll
    for (int i = 0; i < 2; ++i) {
        int rb = wid * 16 + i * 8;
        int row = rb + srow8;
        int cs = (sc ^ (row & 7)) * 8;   // inverse-swizzled global source chunk
        GLL(kb  + ((size_t)bh * SEQ + t * 64 + row) * DKH + cs, lk + rb * 64);
        GLL(vtb + ((size_t)bh * DKH + row) * SEQ + t * 64 + cs, lv + rb * 64);
    }
}

__global__ __launch_bounds__(256) void k_attn(
    const unsigned short* __restrict__ qg,
    const unsigned short* __restrict__ kb,
    const unsigned short* __restrict__ vtb,
    unsigned short* __restrict__ ctxb)
{
    __shared__ unsigned short lds_k[2][64 * 64];
    __shared__ unsigned short lds_v[2][64 * 64];

    int bid = blockIdx.x;
    // XCD-grouped swizzle: all 16 q-tiles of a (b,h) land on the same XCD.
    int x = bid & 7, li = bid >> 3;
    int bh = x * 8 + (li >> 4);
    int qt = li & 15;

    int tid = threadIdx.x, wid = tid >> 6, lane = tid & 63;
    int lq = lane & 31, hi = lane >> 5;
    int srow8 = lane >> 3, sc = lane & 7;

    // Q B-frags: 4 d-steps of 16; lane holds col q = lane&31, k = hi*8+e
    bf16x8 aq[4];
    {
        const unsigned short* qp = qg + ((size_t)bh * SEQ + qt * 128 + wid * 32 + lq) * DKH + hi * 8;
#pragma unroll
        for (int d = 0; d < 4; ++d) aq[d] = *(const bf16x8*)(qp + d * 16);
    }

    float lsum = 0.f;
    f32x16 oa0 = {};   // O^T d-tile 0: col q = lane&31, row d = (r&3)+8(r>>2)+4hi
    f32x16 oa1 = {};   // O^T d-tile 1 (d += 32)

    stage_kv(kb, vtb, &lds_k[0][0], &lds_v[0][0], bh, 0, wid, srow8, sc);
    asm volatile("s_waitcnt vmcnt(0)" ::: "memory");
    __builtin_amdgcn_s_barrier();

    for (int kt = 0; kt < 32; ++kt) {
        int cur = kt & 1;
        if (kt < 31)
            stage_kv(kb, vtb, &lds_k[cur ^ 1][0], &lds_v[cur ^ 1][0], bh, kt + 1, wid, srow8, sc);

        // ---- S^T = K Q^T : 2 kv-tiles x 4 d-steps of 32x32x16 ----
        f32x16 st0 = {}, st1 = {};
        __builtin_amdgcn_s_setprio(1);
#pragma unroll
        for (int ds = 0; ds < 4; ++ds) {
            int ch = ds * 2 + hi;
            bf16x8 kf0 = *(const bf16x8*)(&lds_k[cur][(lq)      * 64 + ((ch ^ (lq & 7)) * 8)]);
            bf16x8 kf1 = *(const bf16x8*)(&lds_k[cur][(32 + lq) * 64 + ((ch ^ (lq & 7)) * 8)]);
            st0 = __builtin_amdgcn_mfma_f32_32x32x16_bf16(kf0, aq[ds], st0, 0, 0, 0);
            st1 = __builtin_amdgcn_mfma_f32_32x32x16_bf16(kf1, aq[ds], st1, 0, 0, 0);
        }
        __builtin_amdgcn_s_setprio(0);

        // ---- P = 2^(S^T); pack own regs 4ks..4ks+3 into B-frags; lsum ----
        short4v w[8];
#pragma unroll
        for (int ks = 0; ks < 4; ++ks) {
            {
                float p0 = __builtin_amdgcn_exp2f(st0[4 * ks + 0]);
                float p1 = __builtin_amdgcn_exp2f(st0[4 * ks + 1]);
                float p2 = __builtin_amdgcn_exp2f(st0[4 * ks + 2]);
                float p3 = __builtin_amdgcn_exp2f(st0[4 * ks + 3]);
                lsum += (p0 + p1) + (p2 + p3);
                bf16x4v pb;
                pb[0] = (__bf16)p0; pb[1] = (__bf16)p1; pb[2] = (__bf16)p2; pb[3] = (__bf16)p3;
                w[ks] = __builtin_bit_cast(short4v, pb);
            }
            {
                float p0 = __builtin_amdgcn_exp2f(st1[4 * ks + 0]);
                float p1 = __builtin_amdgcn_exp2f(st1[4 * ks + 1]);
                float p2 = __builtin_amdgcn_exp2f(st1[4 * ks + 2]);
                float p3 = __builtin_amdgcn_exp2f(st1[4 * ks + 3]);
                lsum += (p0 + p1) + (p2 + p3);
                bf16x4v pb;
                pb[0] = (__bf16)p0; pb[1] = (__bf16)p1; pb[2] = (__bf16)p2; pb[3] = (__bf16)p3;
                w[4 + ks] = __builtin_bit_cast(short4v, pb);
            }
        }

        // ---- O^T += V^T @ P : 2 d-tiles x 8 K=8-steps of 32x32x8 ----
        // V-frag: lane row d = (tile*32 + lq), k = ks*8 + hi*4 + e -> b64 read
        __builtin_amdgcn_s_setprio(1);
#pragma unroll
        for (int ks = 0; ks < 8; ++ks) {
            int co = ((ks ^ (lq & 7)) * 16) + hi * 8;   // byte offset within row
            short4v vf0 = *(const short4v*)((const char*)&lds_v[cur][(lq)      * 64] + co);
            short4v vf1 = *(const short4v*)((const char*)&lds_v[cur][(32 + lq) * 64] + co);
            oa0 = __builtin_amdgcn_mfma_f32_32x32x8bf16_1k(vf0, w[ks], oa0, 0, 0, 0);
            oa1 = __builtin_amdgcn_mfma_f32_32x32x8bf16_1k(vf1, w[ks], oa1, 0, 0, 0);
        }
        __builtin_amdgcn_s_setprio(0);

        if (kt < 31) {
            asm volatile("s_waitcnt vmcnt(0)" ::: "memory");
            __builtin_amdgcn_sched_barrier(0);
            __builtin_amdgcn_s_barrier();
        }
    }

    // ---- epilogue: lsum across hi halves (same q), write ctx[b,s,h,dk] ----
    int b_ = bh >> 4, h = bh & 15;
    lsum += __shfl_xor(lsum, 32);
    float inv = 1.0f / lsum;
    int s_ = qt * 128 + wid * 32 + lq;
    unsigned short* op = ctxb + (((size_t)b_ * SEQ + s_) * NHEAD + h) * DKH;
#pragma unroll
    for (int m = 0; m < 4; ++m) {
        // tile 0: d = 8m + 4hi + {0..3}
        {
            unsigned int u0 = ((unsigned int)f2bf(oa0[4 * m + 1] * inv) << 16) | f2bf(oa0[4 * m + 0] * inv);
            unsigned int u1 = ((unsigned int)f2bf(oa0[4 * m + 3] * inv) << 16) | f2bf(oa0[4 * m + 2] * inv);
            *(uint2v*)(op + 8 * m + 4 * hi) = (uint2v){ u0, u1 };
        }
        // tile 1: d = 32 + 8m + 4hi + {0..3}
        {
            unsigned int u0 = ((unsigned int)f2bf(oa1[4 * m + 1] * inv) << 16) | f2bf(oa1[4 * m + 0] * inv);
            unsigned int u1 = ((unsigned int)f2bf(oa1[4 * m + 3] * inv) << 16) | f2bf(oa1[4 * m + 2] * inv);
            *(uint2v*)(op + 32 + 8 * m + 4 * hi) = (uint2v){ u0, u1 };
        }
    }
}

// ---------------------------------------------------------------------------
// Kernel 4: output projection  out[8192,1024] = ctxb * wob^T + bo  (fp32 out)
// ---------------------------------------------------------------------------
__global__ __launch_bounds__(256) void k_gemm_out(
    const unsigned short* __restrict__ A,    // ctxb [8192][1024] bf16
    const unsigned short* __restrict__ Bw,   // wob  [1024][1024] bf16
    const float* __restrict__ bo,
    float* __restrict__ out)
{
    __shared__ unsigned short lds_a[128 * 32];
    __shared__ unsigned short lds_b[128 * 32];

    const int NT = 1024 / 128;  // 8
    int bid = blockIdx.x;
    int tn = bid % NT, tm = bid / NT;
    int m0 = tm * 128, n0 = tn * 128;
    int tid = threadIdx.x, wid = tid >> 6, lane = tid & 63;
    int wm = wid >> 1, wn = wid & 1;

    f32x4 acc[4][4] = {};

    int srow = lane >> 2;
    int scol = (lane & 3) * 8;

    for (int kt = 0; kt < 32; ++kt) {
        int k0 = kt * 32;
#pragma unroll
        for (int i = 0; i < 2; ++i) {
            int rb = (wid * 2 + i) * 16;
            GLL(A  + (size_t)(m0 + rb + srow) * 1024 + k0 + scol, lds_a + rb * 32);
            GLL(Bw + (size_t)(n0 + rb + srow) * 1024 + k0 + scol, lds_b + rb * 32);
        }
        __syncthreads();
        bf16x8 af[4], bfr[4];
#pragma unroll
        for (int i = 0; i < 4; ++i)
            af[i] = *(const bf16x8*)(lds_a + (wm * 64 + i * 16 + (lane & 15)) * 32 + (lane >> 4) * 8);
#pragma unroll
        for (int j = 0; j < 4; ++j)
            bfr[j] = *(const bf16x8*)(lds_b + (wn * 64 + j * 16 + (lane & 15)) * 32 + (lane >> 4) * 8);
#pragma unroll
        for (int i = 0; i < 4; ++i)
#pragma unroll
            for (int j = 0; j < 4; ++j)
                acc[i][j] = __builtin_amdgcn_mfma_f32_16x16x32_bf16(af[i], bfr[j], acc[i][j], 0, 0, 0);
        __syncthreads();
    }

#pragma unroll
    for (int j = 0; j < 4; ++j) {
        int col = n0 + wn * 64 + j * 16 + (lane & 15);
        float bias = bo[col];
#pragma unroll
        for (int i = 0; i < 4; ++i) {
#pragma unroll
            for (int r = 0; r < 4; ++r) {
                int row = m0 + wm * 64 + i * 16 + (lane >> 4) * 4 + r;
                out[(size_t)row * 1024 + col] = acc[i][j][r] + bias;
            }
        }
    }
}

// ---------------------------------------------------------------------------
extern "C" void kernel_launch(void* const* d_in, const int* in_sizes, int n_in,
                              void* d_out, int out_size, void* d_ws, size_t ws_size,
                              hipStream_t stream)
{
    const float* z  = (const float*)d_in[0];
    const float* Wq = (const float*)d_in[1];
    const float* bq = (const float*)d_in[2];
    const float* Wk = (const float*)d_in[3];
    const float* bk = (const float*)d_in[4];
    const float* Wv = (const float*)d_in[5];
    const float* bv = (const float*)d_in[6];
    const float* Wo = (const float*)d_in[7];
    const float* bo = (const float*)d_in[8];
    float* out = (float*)d_out;

    char* ws = (char*)d_ws;
    unsigned short* zb   = (unsigned short*)(ws);                        // 16 MB
    unsigned short* ctxb = (unsigned short*)(ws);                        // 16 MB (reuse)
    unsigned short* wqkv = (unsigned short*)(ws + (16ull << 20));        //  6 MB
    unsigned short* wob  = (unsigned short*)(ws + (22ull << 20));        //  2 MB
    float*          biasf= (float*)(ws + (24ull << 20));                 // 12 KB
    unsigned short* qb   = (unsigned short*)(ws + (25ull << 20));        // 16 MB
    unsigned short* kb   = (unsigned short*)(ws + (41ull << 20));        // 16 MB
    unsigned short* vtb  = (unsigned short*)(ws + (57ull << 20));        // 16 MB -> 73 MB total

    k_convert<<<8192, 256, 0, stream>>>(z, Wq, Wk, Wv, Wo, bq, bk, bv, zb, wqkv, wob, biasf);
    k_gemm_qkv<<<64 * 24, 256, 0, stream>>>(zb, wqkv, biasf, qb, kb, vtb);
    k_attn<<<NBH * 16, 256, 0, stream>>>(qb, kb, vtb, ctxb);
    k_gemm_out<<<64 * 8, 256, 0, stream>>>(ctxb, wob, bo, out);
}

// Round 8
// 227.362 us; speedup vs baseline: 1.0525x; 1.0525x over previous
//
#include <hip/hip_runtime.h>
#include <stdint.h>

#define D_MODEL 1024
#define NHEAD 16
#define DKH 64
#define BATCH 4
#define SEQ 2048
#define M_ROWS (BATCH*SEQ)   // 8192
#define NBH (BATCH*NHEAD)    // 64

typedef float f32x4 __attribute__((ext_vector_type(4)));
typedef float f32x16 __attribute__((ext_vector_type(16)));
typedef __bf16 bf16x8 __attribute__((ext_vector_type(8)));
typedef __bf16 bf16x4v __attribute__((ext_vector_type(4)));
typedef short short4v __attribute__((ext_vector_type(4)));
typedef unsigned int uint2v __attribute__((ext_vector_type(2)));

__device__ __forceinline__ unsigned short f2bf(float x) {
    __bf16 b = (__bf16)x;                      // hardware v_cvt (RNE)
    return __builtin_bit_cast(unsigned short, b);
}

#define GLL(gsrc, ldst) \
    __builtin_amdgcn_global_load_lds((const __attribute__((address_space(1))) void*)(gsrc), \
                                     (__attribute__((address_space(3))) void*)(ldst), 16, 0, 0)

// ---------------------------------------------------------------------------
// Kernel 1: fp32 -> bf16 conversion / packing
// ---------------------------------------------------------------------------
__global__ __launch_bounds__(256) void k_convert(
    const float* __restrict__ z,  const float* __restrict__ wq,
    const float* __restrict__ wk, const float* __restrict__ wv,
    const float* __restrict__ wo,
    const float* __restrict__ bq, const float* __restrict__ bk,
    const float* __restrict__ bv,
    unsigned short* __restrict__ zb, unsigned short* __restrict__ wqkv,
    unsigned short* __restrict__ wob, float* __restrict__ biasf)
{
    int i = blockIdx.x * 256 + threadIdx.x;   // 0 .. 2097151
    {
        float4 v = ((const float4*)z)[i];
        ushort4 o; o.x = f2bf(v.x); o.y = f2bf(v.y); o.z = f2bf(v.z); o.w = f2bf(v.w);
        ((ushort4*)zb)[i] = o;
    }
    if (i < 262144) {   // 1048576/4 per weight matrix
        float4 v;
        ushort4 o;
        v = ((const float4*)wq)[i];
        o.x=f2bf(v.x); o.y=f2bf(v.y); o.z=f2bf(v.z); o.w=f2bf(v.w);
        ((ushort4*)wqkv)[i] = o;
        v = ((const float4*)wk)[i];
        o.x=f2bf(v.x); o.y=f2bf(v.y); o.z=f2bf(v.z); o.w=f2bf(v.w);
        ((ushort4*)wqkv)[262144 + i] = o;
        v = ((const float4*)wv)[i];
        o.x=f2bf(v.x); o.y=f2bf(v.y); o.z=f2bf(v.z); o.w=f2bf(v.w);
        ((ushort4*)wqkv)[524288 + i] = o;
        v = ((const float4*)wo)[i];
        o.x=f2bf(v.x); o.y=f2bf(v.y); o.z=f2bf(v.z); o.w=f2bf(v.w);
        ((ushort4*)wob)[i] = o;
    }
    if (i < 1024) {
        biasf[i]        = bq[i];
        biasf[1024 + i] = bk[i];
        biasf[2048 + i] = bv[i];
    }
}

// ---------------------------------------------------------------------------
// Kernel 2: QKV projection GEMM  C[8192,3072] = zb * wqkv^T + bias
// Q pre-scaled by log2(e)/8 (softmax scale folded, log2 domain).
// K and V are written to global in MFMA-FRAGMENT ORDER so the attention
// kernel's LDS tiles are lane-linear (zero swizzle, zero bank conflicts):
//   kfrag[bh][kvblk][t32][ds][lane][8]  (lane = hi*32+row31, elems = d)
//   vfrag[bh][kvblk][vt ][ks][lane][4]  (lane = hi*32+d31,   elems = kv)
// ---------------------------------------------------------------------------
__global__ __launch_bounds__(256) void k_gemm_qkv(
    const unsigned short* __restrict__ A,   // [8192][1024] bf16
    const unsigned short* __restrict__ Bw,  // [3072][1024] bf16
    const float* __restrict__ biasf,        // [3072]
    unsigned short* __restrict__ qb, unsigned short* __restrict__ kb,
    unsigned short* __restrict__ vtb)
{
    __shared__ unsigned short lds_a[128 * 32];
    __shared__ unsigned short lds_b[128 * 32];

    const int NT = 3072 / 128;  // 24
    int bid = blockIdx.x;
    int tn = bid % NT, tm = bid / NT;
    int m0 = tm * 128, n0 = tn * 128;
    int tid = threadIdx.x, wid = tid >> 6, lane = tid & 63;
    int wm = wid >> 1, wn = wid & 1;

    f32x4 acc[4][4] = {};

    int srow = lane >> 2;        // 0..15
    int scol = (lane & 3) * 8;   // element offset within 32-col row

    for (int kt = 0; kt < 32; ++kt) {
        int k0 = kt * 32;
#pragma unroll
        for (int i = 0; i < 2; ++i) {
            int rb = (wid * 2 + i) * 16;
            GLL(A  + (size_t)(m0 + rb + srow) * 1024 + k0 + scol, lds_a + rb * 32);
            GLL(Bw + (size_t)(n0 + rb + srow) * 1024 + k0 + scol, lds_b + rb * 32);
        }
        __syncthreads();
        bf16x8 af[4], bfr[4];
#pragma unroll
        for (int i = 0; i < 4; ++i)
            af[i] = *(const bf16x8*)(lds_a + (wm * 64 + i * 16 + (lane & 15)) * 32 + (lane >> 4) * 8);
#pragma unroll
        for (int j = 0; j < 4; ++j)
            bfr[j] = *(const bf16x8*)(lds_b + (wn * 64 + j * 16 + (lane & 15)) * 32 + (lane >> 4) * 8);
#pragma unroll
        for (int i = 0; i < 4; ++i)
#pragma unroll
            for (int j = 0; j < 4; ++j)
                acc[i][j] = __builtin_amdgcn_mfma_f32_16x16x32_bf16(af[i], bfr[j], acc[i][j], 0, 0, 0);
        __syncthreads();
    }

    const float QSC = 0.18033688011112042f;  // log2(e) / sqrt(64)
    int t = n0 >> 10;  // 0=Q 1=K 2=V
#pragma unroll
    for (int j = 0; j < 4; ++j) {
        int col = n0 + wn * 64 + j * 16 + (lane & 15);
        float bias = biasf[col];
        int d  = col & 1023;
        int h  = d >> 6;
        int dk = d & 63;
#pragma unroll
        for (int i = 0; i < 4; ++i) {
#pragma unroll
            for (int r = 0; r < 4; ++r) {
                int row = m0 + wm * 64 + i * 16 + (lane >> 4) * 4 + r;
                float v = acc[i][j][r] + bias;
                if (t == 0) v *= QSC;            // uniform per block
                unsigned short bv16 = f2bf(v);
                int b_ = row >> 11, s_ = row & 2047;
                int bh = b_ * NHEAD + h;
                if (t == 0) {
                    qb[((size_t)bh * SEQ + s_) * DKH + dk] = bv16;
                } else if (t == 1) {
                    // K fragment order: tile=(bh,s>>6); within: t32=row64>>5,
                    // frag (t32*4+ds), lane = hi*32 + (row64&31), elem = dk&7
                    int kvblk = s_ >> 6, r64 = s_ & 63;
                    int t32 = r64 >> 5, l5 = r64 & 31;
                    int ds = dk >> 4, hi2 = (dk >> 3) & 1, e = dk & 7;
                    kb[((size_t)(bh * 32 + kvblk)) * 4096 +
                       (t32 * 4 + ds) * 512 + (hi2 * 32 + l5) * 8 + e] = bv16;
                } else {
                    // V fragment order: lane row = d31, k elems = kv
                    int kvblk = s_ >> 6, kv64 = s_ & 63;
                    int ks = kv64 >> 3, hi2 = (kv64 >> 2) & 1, e = kv64 & 3;
                    int vt = dk >> 5, l5 = dk & 31;
                    vtb[((size_t)(bh * 32 + kvblk)) * 4096 +
                        (vt * 8 + ks) * 256 + (hi2 * 32 + l5) * 4 + e] = bv16;
                }
            }
        }
    }
}

// ---------------------------------------------------------------------------
// Kernel 3: flash attention, 32x32 MFMA, fragment-order K/V, 8 waves x 32 q.
//   All LDS reads are wave-uniform-base + lane-contiguous (b128 at lane*16B,
//   b64 at lane*8B) -> conflict-free by construction. GLL staging is one
//   linear 8KB block per matrix per tile (1 GLL/thread/matrix).
//   P = exp2(S^T) unnormalized; PV B-frag = own C-regs [4ks..4ks+3].
// ---------------------------------------------------------------------------
__global__ __launch_bounds__(512) void k_attn(
    const unsigned short* __restrict__ qg,
    const unsigned short* __restrict__ kb,
    const unsigned short* __restrict__ vtb,
    unsigned short* __restrict__ ctxb)
{
    __shared__ unsigned short lds_k[2][4096];
    __shared__ unsigned short lds_v[2][4096];

    int bid = blockIdx.x;
    // XCD-grouped swizzle: the 8 q-tiles of a (b,h) land on the same XCD.
    int x = bid & 7, li = bid >> 3;          // 512 blocks: 64 per XCD
    int bh = x * 8 + (li >> 3);
    int qt = li & 7;

    int tid = threadIdx.x, wid = tid >> 6, lane = tid & 63;
    int lq = lane & 31, hi = lane >> 5;

    // Q B-frags: col q = lane&31, k(d) = ds*16 + hi*8 + e
    bf16x8 aq[4];
    {
        const unsigned short* qp = qg + ((size_t)bh * SEQ + qt * 256 + wid * 32 + lq) * DKH + hi * 8;
#pragma unroll
        for (int d = 0; d < 4; ++d) aq[d] = *(const bf16x8*)(qp + d * 16);
    }

    float lsum = 0.f;
    f32x16 oa0 = {};   // O^T d-tile 0: col q = lane&31, row d = (r&3)+8(r>>2)+4hi
    f32x16 oa1 = {};   // O^T d-tile 1 (d += 32)

    const unsigned short* kbase = kb  + (size_t)bh * 32 * 4096;
    const unsigned short* vbase = vtb + (size_t)bh * 32 * 4096;
    int so = wid * 512 + lane * 8;   // element offset: wave chunk + lane*16B

    GLL(kbase + so, &lds_k[0][wid * 512]);
    GLL(vbase + so, &lds_v[0][wid * 512]);
    asm volatile("s_waitcnt vmcnt(0)" ::: "memory");
    __builtin_amdgcn_s_barrier();

    for (int kt = 0; kt < 32; ++kt) {
        int cur = kt & 1;
        if (kt < 31) {
            GLL(kbase + (size_t)(kt + 1) * 4096 + so, &lds_k[cur ^ 1][wid * 512]);
            GLL(vbase + (size_t)(kt + 1) * 4096 + so, &lds_v[cur ^ 1][wid * 512]);
        }

        // ---- S^T = K Q^T : 2 kv-tiles x 4 d-steps of 32x32x16 ----
        f32x16 st0 = {}, st1 = {};
        __builtin_amdgcn_s_setprio(1);
#pragma unroll
        for (int ds = 0; ds < 4; ++ds) {
            bf16x8 kf0 = *(const bf16x8*)(&lds_k[cur][(ds)     * 512 + lane * 8]);
            bf16x8 kf1 = *(const bf16x8*)(&lds_k[cur][(4 + ds) * 512 + lane * 8]);
            st0 = __builtin_amdgcn_mfma_f32_32x32x16_bf16(kf0, aq[ds], st0, 0, 0, 0);
            st1 = __builtin_amdgcn_mfma_f32_32x32x16_bf16(kf1, aq[ds], st1, 0, 0, 0);
        }
        __builtin_amdgcn_s_setprio(0);

        // ---- P = 2^(S^T); B-frag[ks] = own C-regs [4ks..4ks+3]; lsum ----
        short4v w[8];
#pragma unroll
        for (int ks = 0; ks < 4; ++ks) {
            {
                float p0 = __builtin_amdgcn_exp2f(st0[4 * ks + 0]);
                float p1 = __builtin_amdgcn_exp2f(st0[4 * ks + 1]);
                float p2 = __builtin_amdgcn_exp2f(st0[4 * ks + 2]);
                float p3 = __builtin_amdgcn_exp2f(st0[4 * ks + 3]);
                lsum += (p0 + p1) + (p2 + p3);
                bf16x4v pb;
                pb[0] = (__bf16)p0; pb[1] = (__bf16)p1; pb[2] = (__bf16)p2; pb[3] = (__bf16)p3;
                w[ks] = __builtin_bit_cast(short4v, pb);
            }
            {
                float p0 = __builtin_amdgcn_exp2f(st1[4 * ks + 0]);
                float p1 = __builtin_amdgcn_exp2f(st1[4 * ks + 1]);
                float p2 = __builtin_amdgcn_exp2f(st1[4 * ks + 2]);
                float p3 = __builtin_amdgcn_exp2f(st1[4 * ks + 3]);
                lsum += (p0 + p1) + (p2 + p3);
                bf16x4v pb;
                pb[0] = (__bf16)p0; pb[1] = (__bf16)p1; pb[2] = (__bf16)p2; pb[3] = (__bf16)p3;
                w[4 + ks] = __builtin_bit_cast(short4v, pb);
            }
        }

        // ---- O^T += V^T @ P : 2 d-tiles x 8 K=8-steps of 32x32x8 ----
        __builtin_amdgcn_s_setprio(1);
#pragma unroll
        for (int ks = 0; ks < 8; ++ks) {
            short4v vf0 = *(const short4v*)(&lds_v[cur][(ks)     * 256 + lane * 4]);
            short4v vf1 = *(const short4v*)(&lds_v[cur][(8 + ks) * 256 + lane * 4]);
            oa0 = __builtin_amdgcn_mfma_f32_32x32x8bf16_1k(vf0, w[ks], oa0, 0, 0, 0);
            oa1 = __builtin_amdgcn_mfma_f32_32x32x8bf16_1k(vf1, w[ks], oa1, 0, 0, 0);
        }
        __builtin_amdgcn_s_setprio(0);

        if (kt < 31) {
            asm volatile("s_waitcnt vmcnt(0)" ::: "memory");
            __builtin_amdgcn_sched_barrier(0);
            __builtin_amdgcn_s_barrier();
        }
    }

    // ---- epilogue: lsum across hi halves (same q), write ctx[b,s,h,dk] ----
    int b_ = bh >> 4, h = bh & 15;
    lsum += __shfl_xor(lsum, 32);
    float inv = 1.0f / lsum;
    int s_ = qt * 256 + wid * 32 + lq;
    unsigned short* op = ctxb + (((size_t)b_ * SEQ + s_) * NHEAD + h) * DKH;
#pragma unroll
    for (int m = 0; m < 4; ++m) {
        {
            unsigned int u0 = ((unsigned int)f2bf(oa0[4 * m + 1] * inv) << 16) | f2bf(oa0[4 * m + 0] * inv);
            unsigned int u1 = ((unsigned int)f2bf(oa0[4 * m + 3] * inv) << 16) | f2bf(oa0[4 * m + 2] * inv);
            *(uint2v*)(op + 8 * m + 4 * hi) = (uint2v){ u0, u1 };
        }
        {
            unsigned int u0 = ((unsigned int)f2bf(oa1[4 * m + 1] * inv) << 16) | f2bf(oa1[4 * m + 0] * inv);
            unsigned int u1 = ((unsigned int)f2bf(oa1[4 * m + 3] * inv) << 16) | f2bf(oa1[4 * m + 2] * inv);
            *(uint2v*)(op + 32 + 8 * m + 4 * hi) = (uint2v){ u0, u1 };
        }
    }
}

// ---------------------------------------------------------------------------
// Kernel 4: output projection  out[8192,1024] = ctxb * wob^T + bo  (fp32 out)
// ---------------------------------------------------------------------------
__global__ __launch_bounds__(256) void k_gemm_out(
    const unsigned short* __restrict__ A,    // ctxb [8192][1024] bf16
    const unsigned short* __restrict__ Bw,   // wob  [1024][1024] bf16
    const float* __restrict__ bo,
    float* __restrict__ out)
{
    __shared__ unsigned short lds_a[128 * 32];
    __shared__ unsigned short lds_b[128 * 32];

    const int NT = 1024 / 128;  // 8
    int bid = blockIdx.x;
    int tn = bid % NT, tm = bid / NT;
    int m0 = tm * 128, n0 = tn * 128;
    int tid = threadIdx.x, wid = tid >> 6, lane = tid & 63;
    int wm = wid >> 1, wn = wid & 1;

    f32x4 acc[4][4] = {};

    int srow = lane >> 2;
    int scol = (lane & 3) * 8;

    for (int kt = 0; kt < 32; ++kt) {
        int k0 = kt * 32;
#pragma unroll
        for (int i = 0; i < 2; ++i) {
            int rb = (wid * 2 + i) * 16;
            GLL(A  + (size_t)(m0 + rb + srow) * 1024 + k0 + scol, lds_a + rb * 32);
            GLL(Bw + (size_t)(n0 + rb + srow) * 1024 + k0 + scol, lds_b + rb * 32);
        }
        __syncthreads();
        bf16x8 af[4], bfr[4];
#pragma unroll
        for (int i = 0; i < 4; ++i)
            af[i] = *(const bf16x8*)(lds_a + (wm * 64 + i * 16 + (lane & 15)) * 32 + (lane >> 4) * 8);
#pragma unroll
        for (int j = 0; j < 4; ++j)
            bfr[j] = *(const bf16x8*)(lds_b + (wn * 64 + j * 16 + (lane & 15)) * 32 + (lane >> 4) * 8);
#pragma unroll
        for (int i = 0; i < 4; ++i)
#pragma unroll
            for (int j = 0; j < 4; ++j)
                acc[i][j] = __builtin_amdgcn_mfma_f32_16x16x32_bf16(af[i], bfr[j], acc[i][j], 0, 0, 0);
        __syncthreads();
    }

#pragma unroll
    for (int j = 0; j < 4; ++j) {
        int col = n0 + wn * 64 + j * 16 + (lane & 15);
        float bias = bo[col];
#pragma unroll
        for (int i = 0; i < 4; ++i) {
#pragma unroll
            for (int r = 0; r < 4; ++r) {
                int row = m0 + wm * 64 + i * 16 + (lane >> 4) * 4 + r;
                out[(size_t)row * 1024 + col] = acc[i][j][r] + bias;
            }
        }
    }
}

// ---------------------------------------------------------------------------
extern "C" void kernel_launch(void* const* d_in, const int* in_sizes, int n_in,
                              void* d_out, int out_size, void* d_ws, size_t ws_size,
                              hipStream_t stream)
{
    const float* z  = (const float*)d_in[0];
    const float* Wq = (const float*)d_in[1];
    const float* bq = (const float*)d_in[2];
    const float* Wk = (const float*)d_in[3];
    const float* bk = (const float*)d_in[4];
    const float* Wv = (const float*)d_in[5];
    const float* bv = (const float*)d_in[6];
    const float* Wo = (const float*)d_in[7];
    const float* bo = (const float*)d_in[8];
    float* out = (float*)d_out;

    char* ws = (char*)d_ws;
    unsigned short* zb   = (unsigned short*)(ws);                        // 16 MB
    unsigned short* ctxb = (unsigned short*)(ws);                        // 16 MB (reuse)
    unsigned short* wqkv = (unsigned short*)(ws + (16ull << 20));        //  6 MB
    unsigned short* wob  = (unsigned short*)(ws + (22ull << 20));        //  2 MB
    float*          biasf= (float*)(ws + (24ull << 20));                 // 12 KB
    unsigned short* qb   = (unsigned short*)(ws + (25ull << 20));        // 16 MB
    unsigned short* kb   = (unsigned short*)(ws + (41ull << 20));        // 16 MB
    unsigned short* vtb  = (unsigned short*)(ws + (57ull << 20));        // 16 MB -> 73 MB total

    k_convert<<<8192, 256, 0, stream>>>(z, Wq, Wk, Wv, Wo, bq, bk, bv, zb, wqkv, wob, biasf);
    k_gemm_qkv<<<64 * 24, 256, 0, stream>>>(zb, wqkv, biasf, qb, kb, vtb);
    k_attn<<<NBH * 8, 512, 0, stream>>>(qb, kb, vtb, ctxb);
    k_gemm_out<<<64 * 8, 256, 0, stream>>>(ctxb, wob, bo, out);
}

// Round 9
// 223.349 us; speedup vs baseline: 1.0714x; 1.0180x over previous
//
#include <hip/hip_runtime.h>
#include <stdint.h>

#define D_MODEL 1024
#define NHEAD 16
#define DKH 64
#define BATCH 4
#define SEQ 2048
#define M_ROWS (BATCH*SEQ)   // 8192
#define NBH (BATCH*NHEAD)    // 64

typedef float f32x4 __attribute__((ext_vector_type(4)));
typedef float f32x16 __attribute__((ext_vector_type(16)));
typedef __bf16 bf16x8 __attribute__((ext_vector_type(8)));
typedef __bf16 bf16x4v __attribute__((ext_vector_type(4)));
typedef short short4v __attribute__((ext_vector_type(4)));
typedef unsigned int uint2v __attribute__((ext_vector_type(2)));

__device__ __forceinline__ unsigned short f2bf(float x) {
    __bf16 b = (__bf16)x;                      // hardware v_cvt (RNE)
    return __builtin_bit_cast(unsigned short, b);
}

#define GLL(gsrc, ldst) \
    __builtin_amdgcn_global_load_lds((const __attribute__((address_space(1))) void*)(gsrc), \
                                     (__attribute__((address_space(3))) void*)(ldst), 16, 0, 0)

// ---------------------------------------------------------------------------
// Kernel 1: fp32 -> bf16 conversion / packing
// ---------------------------------------------------------------------------
__global__ __launch_bounds__(256) void k_convert(
    const float* __restrict__ z,  const float* __restrict__ wq,
    const float* __restrict__ wk, const float* __restrict__ wv,
    const float* __restrict__ wo,
    const float* __restrict__ bq, const float* __restrict__ bk,
    const float* __restrict__ bv,
    unsigned short* __restrict__ zb, unsigned short* __restrict__ wqkv,
    unsigned short* __restrict__ wob, float* __restrict__ biasf)
{
    int i = blockIdx.x * 256 + threadIdx.x;   // 0 .. 2097151
    {
        float4 v = ((const float4*)z)[i];
        ushort4 o; o.x = f2bf(v.x); o.y = f2bf(v.y); o.z = f2bf(v.z); o.w = f2bf(v.w);
        ((ushort4*)zb)[i] = o;
    }
    if (i < 262144) {   // 1048576/4 per weight matrix
        float4 v;
        ushort4 o;
        v = ((const float4*)wq)[i];
        o.x=f2bf(v.x); o.y=f2bf(v.y); o.z=f2bf(v.z); o.w=f2bf(v.w);
        ((ushort4*)wqkv)[i] = o;
        v = ((const float4*)wk)[i];
        o.x=f2bf(v.x); o.y=f2bf(v.y); o.z=f2bf(v.z); o.w=f2bf(v.w);
        ((ushort4*)wqkv)[262144 + i] = o;
        v = ((const float4*)wv)[i];
        o.x=f2bf(v.x); o.y=f2bf(v.y); o.z=f2bf(v.z); o.w=f2bf(v.w);
        ((ushort4*)wqkv)[524288 + i] = o;
        v = ((const float4*)wo)[i];
        o.x=f2bf(v.x); o.y=f2bf(v.y); o.z=f2bf(v.z); o.w=f2bf(v.w);
        ((ushort4*)wob)[i] = o;
    }
    if (i < 1024) {
        biasf[i]        = bq[i];
        biasf[1024 + i] = bk[i];
        biasf[2048 + i] = bv[i];
    }
}

// ---------------------------------------------------------------------------
// Kernel 2: QKV projection GEMM  C[8192,3072] = zb * wqkv^T + bias
// Q pre-scaled by log2(e)/8. K and V written in MFMA-fragment order:
//   kfrag[bh][kvblk][t32*4+ds][lane][8]   vfrag[bh][kvblk][vt*8+ks][lane][4]
// ---------------------------------------------------------------------------
__global__ __launch_bounds__(256) void k_gemm_qkv(
    const unsigned short* __restrict__ A,   // [8192][1024] bf16
    const unsigned short* __restrict__ Bw,  // [3072][1024] bf16
    const float* __restrict__ biasf,        // [3072]
    unsigned short* __restrict__ qb, unsigned short* __restrict__ kb,
    unsigned short* __restrict__ vtb)
{
    __shared__ unsigned short lds_a[128 * 32];
    __shared__ unsigned short lds_b[128 * 32];

    const int NT = 3072 / 128;  // 24
    int bid = blockIdx.x;
    int tn = bid % NT, tm = bid / NT;
    int m0 = tm * 128, n0 = tn * 128;
    int tid = threadIdx.x, wid = tid >> 6, lane = tid & 63;
    int wm = wid >> 1, wn = wid & 1;

    f32x4 acc[4][4] = {};

    int srow = lane >> 2;        // 0..15
    int scol = (lane & 3) * 8;   // element offset within 32-col row

    for (int kt = 0; kt < 32; ++kt) {
        int k0 = kt * 32;
#pragma unroll
        for (int i = 0; i < 2; ++i) {
            int rb = (wid * 2 + i) * 16;
            GLL(A  + (size_t)(m0 + rb + srow) * 1024 + k0 + scol, lds_a + rb * 32);
            GLL(Bw + (size_t)(n0 + rb + srow) * 1024 + k0 + scol, lds_b + rb * 32);
        }
        __syncthreads();
        bf16x8 af[4], bfr[4];
#pragma unroll
        for (int i = 0; i < 4; ++i)
            af[i] = *(const bf16x8*)(lds_a + (wm * 64 + i * 16 + (lane & 15)) * 32 + (lane >> 4) * 8);
#pragma unroll
        for (int j = 0; j < 4; ++j)
            bfr[j] = *(const bf16x8*)(lds_b + (wn * 64 + j * 16 + (lane & 15)) * 32 + (lane >> 4) * 8);
#pragma unroll
        for (int i = 0; i < 4; ++i)
#pragma unroll
            for (int j = 0; j < 4; ++j)
                acc[i][j] = __builtin_amdgcn_mfma_f32_16x16x32_bf16(af[i], bfr[j], acc[i][j], 0, 0, 0);
        __syncthreads();
    }

    const float QSC = 0.18033688011112042f;  // log2(e) / sqrt(64)
    int t = n0 >> 10;  // 0=Q 1=K 2=V
#pragma unroll
    for (int j = 0; j < 4; ++j) {
        int col = n0 + wn * 64 + j * 16 + (lane & 15);
        float bias = biasf[col];
        int d  = col & 1023;
        int h  = d >> 6;
        int dk = d & 63;
#pragma unroll
        for (int i = 0; i < 4; ++i) {
#pragma unroll
            for (int r = 0; r < 4; ++r) {
                int row = m0 + wm * 64 + i * 16 + (lane >> 4) * 4 + r;
                float v = acc[i][j][r] + bias;
                if (t == 0) v *= QSC;            // uniform per block
                unsigned short bv16 = f2bf(v);
                int b_ = row >> 11, s_ = row & 2047;
                int bh = b_ * NHEAD + h;
                if (t == 0) {
                    qb[((size_t)bh * SEQ + s_) * DKH + dk] = bv16;
                } else if (t == 1) {
                    int kvblk = s_ >> 6, r64 = s_ & 63;
                    int t32 = r64 >> 5, l5 = r64 & 31;
                    int ds = dk >> 4, hi2 = (dk >> 3) & 1, e = dk & 7;
                    kb[((size_t)(bh * 32 + kvblk)) * 4096 +
                       (t32 * 4 + ds) * 512 + (hi2 * 32 + l5) * 8 + e] = bv16;
                } else {
                    int kvblk = s_ >> 6, kv64 = s_ & 63;
                    int ks = kv64 >> 3, hi2 = (kv64 >> 2) & 1, e = kv64 & 3;
                    int vt = dk >> 5, l5 = dk & 31;
                    vtb[((size_t)(bh * 32 + kvblk)) * 4096 +
                        (vt * 8 + ks) * 256 + (hi2 * 32 + l5) * 4 + e] = bv16;
                }
            }
        }
    }
}

// ---------------------------------------------------------------------------
// Kernel 3: flash attention, 32x32 MFMA, fragment-order K/V, 8 waves x 32 q,
// TWO-TILE SOFTWARE PIPELINE: step kt computes QK^T(kt) and PV(kt-1) as
// interleaved independent MFMA chains (4 accumulators feed the in-order
// pipe), then exp(kt). V staged one tile behind K; w double-state (wA/wB)
// via even/odd unrolled pair loop (all indices compile-time).
// ---------------------------------------------------------------------------

// One pipelined step: QK^T from LDSK, PV(prev) from LDSV using WPREV,
// exp results into WCUR. DO_PV is a compile-time bool.
#define ATTN_STEP(LDSK, LDSV, WPREV, WCUR, DO_PV)                                   \
    {                                                                               \
        f32x16 st0 = {}, st1 = {};                                                  \
        __builtin_amdgcn_s_setprio(1);                                              \
        _Pragma("unroll")                                                           \
        for (int ds = 0; ds < 4; ++ds) {                                            \
            bf16x8 kf0 = *(const bf16x8*)(&(LDSK)[(ds) * 512 + lane * 8]);          \
            bf16x8 kf1 = *(const bf16x8*)(&(LDSK)[(4 + ds) * 512 + lane * 8]);      \
            st0 = __builtin_amdgcn_mfma_f32_32x32x16_bf16(kf0, aq[ds], st0, 0, 0, 0); \
            st1 = __builtin_amdgcn_mfma_f32_32x32x16_bf16(kf1, aq[ds], st1, 0, 0, 0); \
            if (DO_PV) {                                                            \
                short4v vf0 = *(const short4v*)(&(LDSV)[(2 * ds) * 256 + lane * 4]);        \
                short4v vf1 = *(const short4v*)(&(LDSV)[(8 + 2 * ds) * 256 + lane * 4]);    \
                oa0 = __builtin_amdgcn_mfma_f32_32x32x8bf16_1k(vf0, WPREV[2 * ds], oa0, 0, 0, 0); \
                oa1 = __builtin_amdgcn_mfma_f32_32x32x8bf16_1k(vf1, WPREV[2 * ds], oa1, 0, 0, 0); \
                short4v vf2 = *(const short4v*)(&(LDSV)[(2 * ds + 1) * 256 + lane * 4]);    \
                short4v vf3 = *(const short4v*)(&(LDSV)[(8 + 2 * ds + 1) * 256 + lane * 4]);\
                oa0 = __builtin_amdgcn_mfma_f32_32x32x8bf16_1k(vf2, WPREV[2 * ds + 1], oa0, 0, 0, 0); \
                oa1 = __builtin_amdgcn_mfma_f32_32x32x8bf16_1k(vf3, WPREV[2 * ds + 1], oa1, 0, 0, 0); \
            }                                                                       \
        }                                                                           \
        __builtin_amdgcn_s_setprio(0);                                              \
        _Pragma("unroll")                                                           \
        for (int ks = 0; ks < 4; ++ks) {                                            \
            {                                                                       \
                float p0 = __builtin_amdgcn_exp2f(st0[4 * ks + 0]);                 \
                float p1 = __builtin_amdgcn_exp2f(st0[4 * ks + 1]);                 \
                float p2 = __builtin_amdgcn_exp2f(st0[4 * ks + 2]);                 \
                float p3 = __builtin_amdgcn_exp2f(st0[4 * ks + 3]);                 \
                lsum += (p0 + p1) + (p2 + p3);                                      \
                bf16x4v pb;                                                         \
                pb[0] = (__bf16)p0; pb[1] = (__bf16)p1; pb[2] = (__bf16)p2; pb[3] = (__bf16)p3; \
                WCUR[ks] = __builtin_bit_cast(short4v, pb);                         \
            }                                                                       \
            {                                                                       \
                float p0 = __builtin_amdgcn_exp2f(st1[4 * ks + 0]);                 \
                float p1 = __builtin_amdgcn_exp2f(st1[4 * ks + 1]);                 \
                float p2 = __builtin_amdgcn_exp2f(st1[4 * ks + 2]);                 \
                float p3 = __builtin_amdgcn_exp2f(st1[4 * ks + 3]);                 \
                lsum += (p0 + p1) + (p2 + p3);                                      \
                bf16x4v pb;                                                         \
                pb[0] = (__bf16)p0; pb[1] = (__bf16)p1; pb[2] = (__bf16)p2; pb[3] = (__bf16)p3; \
                WCUR[4 + ks] = __builtin_bit_cast(short4v, pb);                     \
            }                                                                       \
        }                                                                           \
    }

#define DRAIN_BARRIER()                                         \
    asm volatile("s_waitcnt vmcnt(0)" ::: "memory");            \
    __builtin_amdgcn_sched_barrier(0);                          \
    __builtin_amdgcn_s_barrier();

__global__ __launch_bounds__(512) void k_attn(
    const unsigned short* __restrict__ qg,
    const unsigned short* __restrict__ kb,
    const unsigned short* __restrict__ vtb,
    unsigned short* __restrict__ ctxb)
{
    __shared__ unsigned short lds_k[2][4096];
    __shared__ unsigned short lds_v[2][4096];

    int bid = blockIdx.x;
    // XCD-grouped swizzle: the 8 q-tiles of a (b,h) land on the same XCD.
    int x = bid & 7, li = bid >> 3;          // 512 blocks: 64 per XCD
    int bh = x * 8 + (li >> 3);
    int qt = li & 7;

    int tid = threadIdx.x, wid = tid >> 6, lane = tid & 63;
    int lq = lane & 31, hi = lane >> 5;

    // Q B-frags: col q = lane&31, k(d) = ds*16 + hi*8 + e
    bf16x8 aq[4];
    {
        const unsigned short* qp = qg + ((size_t)bh * SEQ + qt * 256 + wid * 32 + lq) * DKH + hi * 8;
#pragma unroll
        for (int d = 0; d < 4; ++d) aq[d] = *(const bf16x8*)(qp + d * 16);
    }

    float lsum = 0.f;
    f32x16 oa0 = {};   // O^T d-tile 0: col q = lane&31, row d = (r&3)+8(r>>2)+4hi
    f32x16 oa1 = {};   // O^T d-tile 1 (d += 32)
    short4v wA[8], wB[8];

    const unsigned short* kbase = kb  + (size_t)bh * 32 * 4096;
    const unsigned short* vbase = vtb + (size_t)bh * 32 * 4096;
    int so = wid * 512 + lane * 8;   // element offset: wave chunk + lane*16B
    unsigned short* ldk0 = &lds_k[0][wid * 512];
    unsigned short* ldk1 = &lds_k[1][wid * 512];
    unsigned short* ldv0 = &lds_v[0][wid * 512];
    unsigned short* ldv1 = &lds_v[1][wid * 512];

    // ---- prologue: K0 ----
    GLL(kbase + so, ldk0);
    DRAIN_BARRIER();

    // ---- kt = 0: stage K1 + V0; QK^T(0); exp -> wA ----
    GLL(kbase + 4096 + so, ldk1);
    GLL(vbase + so, ldv0);
    ATTN_STEP(lds_k[0], lds_v[0], wB, wA, false);
    DRAIN_BARRIER();

    // ---- steady state: pairs (kt odd, kt even) ----
    for (int t = 1; t < 31; t += 2) {
        // kt = t (odd): stage K[t+1]->buf0, V[t]->buf1; QKT from buf1; PV(t-1) from V buf0
        GLL(kbase + (size_t)(t + 1) * 4096 + so, ldk0);
        GLL(vbase + (size_t)t * 4096 + so, ldv1);
        ATTN_STEP(lds_k[1], lds_v[0], wA, wB, true);
        DRAIN_BARRIER();
        // kt = t+1 (even): stage K[t+2]->buf1, V[t+1]->buf0; QKT from buf0; PV(t) from V buf1
        if (t + 2 < 32) GLL(kbase + (size_t)(t + 2) * 4096 + so, ldk1);
        GLL(vbase + (size_t)(t + 1) * 4096 + so, ldv0);
        ATTN_STEP(lds_k[0], lds_v[1], wB, wA, true);
        DRAIN_BARRIER();
    }

    // ---- kt = 31 (odd): stage V[31]; QKT(31); PV(30); exp -> wB ----
    GLL(vbase + (size_t)31 * 4096 + so, ldv1);
    ATTN_STEP(lds_k[1], lds_v[0], wA, wB, true);
    DRAIN_BARRIER();

    // ---- final PV(31) ----
    __builtin_amdgcn_s_setprio(1);
#pragma unroll
    for (int ks = 0; ks < 8; ++ks) {
        short4v vf0 = *(const short4v*)(&lds_v[1][(ks) * 256 + lane * 4]);
        short4v vf1 = *(const short4v*)(&lds_v[1][(8 + ks) * 256 + lane * 4]);
        oa0 = __builtin_amdgcn_mfma_f32_32x32x8bf16_1k(vf0, wB[ks], oa0, 0, 0, 0);
        oa1 = __builtin_amdgcn_mfma_f32_32x32x8bf16_1k(vf1, wB[ks], oa1, 0, 0, 0);
    }
    __builtin_amdgcn_s_setprio(0);

    // ---- epilogue: lsum across hi halves (same q), write ctx[b,s,h,dk] ----
    int b_ = bh >> 4, h = bh & 15;
    lsum += __shfl_xor(lsum, 32);
    float inv = 1.0f / lsum;
    int s_ = qt * 256 + wid * 32 + lq;
    unsigned short* op = ctxb + (((size_t)b_ * SEQ + s_) * NHEAD + h) * DKH;
#pragma unroll
    for (int m = 0; m < 4; ++m) {
        {
            unsigned int u0 = ((unsigned int)f2bf(oa0[4 * m + 1] * inv) << 16) | f2bf(oa0[4 * m + 0] * inv);
            unsigned int u1 = ((unsigned int)f2bf(oa0[4 * m + 3] * inv) << 16) | f2bf(oa0[4 * m + 2] * inv);
            *(uint2v*)(op + 8 * m + 4 * hi) = (uint2v){ u0, u1 };
        }
        {
            unsigned int u0 = ((unsigned int)f2bf(oa1[4 * m + 1] * inv) << 16) | f2bf(oa1[4 * m + 0] * inv);
            unsigned int u1 = ((unsigned int)f2bf(oa1[4 * m + 3] * inv) << 16) | f2bf(oa1[4 * m + 2] * inv);
            *(uint2v*)(op + 32 + 8 * m + 4 * hi) = (uint2v){ u0, u1 };
        }
    }
}

// ---------------------------------------------------------------------------
// Kernel 4: output projection  out[8192,1024] = ctxb * wob^T + bo  (fp32 out)
// ---------------------------------------------------------------------------
__global__ __launch_bounds__(256) void k_gemm_out(
    const unsigned short* __restrict__ A,    // ctxb [8192][1024] bf16
    const unsigned short* __restrict__ Bw,   // wob  [1024][1024] bf16
    const float* __restrict__ bo,
    float* __restrict__ out)
{
    __shared__ unsigned short lds_a[128 * 32];
    __shared__ unsigned short lds_b[128 * 32];

    const int NT = 1024 / 128;  // 8
    int bid = blockIdx.x;
    int tn = bid % NT, tm = bid / NT;
    int m0 = tm * 128, n0 = tn * 128;
    int tid = threadIdx.x, wid = tid >> 6, lane = tid & 63;
    int wm = wid >> 1, wn = wid & 1;

    f32x4 acc[4][4] = {};

    int srow = lane >> 2;
    int scol = (lane & 3) * 8;

    for (int kt = 0; kt < 32; ++kt) {
        int k0 = kt * 32;
#pragma unroll
        for (int i = 0; i < 2; ++i) {
            int rb = (wid * 2 + i) * 16;
            GLL(A  + (size_t)(m0 + rb + srow) * 1024 + k0 + scol, lds_a + rb * 32);
            GLL(Bw + (size_t)(n0 + rb + srow) * 1024 + k0 + scol, lds_b + rb * 32);
        }
        __syncthreads();
        bf16x8 af[4], bfr[4];
#pragma unroll
        for (int i = 0; i < 4; ++i)
            af[i] = *(const bf16x8*)(lds_a + (wm * 64 + i * 16 + (lane & 15)) * 32 + (lane >> 4) * 8);
#pragma unroll
        for (int j = 0; j < 4; ++j)
            bfr[j] = *(const bf16x8*)(lds_b + (wn * 64 + j * 16 + (lane & 15)) * 32 + (lane >> 4) * 8);
#pragma unroll
        for (int i = 0; i < 4; ++i)
#pragma unroll
            for (int j = 0; j < 4; ++j)
                acc[i][j] = __builtin_amdgcn_mfma_f32_16x16x32_bf16(af[i], bfr[j], acc[i][j], 0, 0, 0);
        __syncthreads();
    }

#pragma unroll
    for (int j = 0; j < 4; ++j) {
        int col = n0 + wn * 64 + j * 16 + (lane & 15);
        float bias = bo[col];
#pragma unroll
        for (int i = 0; i < 4; ++i) {
#pragma unroll
            for (int r = 0; r < 4; ++r) {
                int row = m0 + wm * 64 + i * 16 + (lane >> 4) * 4 + r;
                out[(size_t)row * 1024 + col] = acc[i][j][r] + bias;
            }
        }
    }
}

// ---------------------------------------------------------------------------
extern "C" void kernel_launch(void* const* d_in, const int* in_sizes, int n_in,
                              void* d_out, int out_size, void* d_ws, size_t ws_size,
                              hipStream_t stream)
{
    const float* z  = (const float*)d_in[0];
    const float* Wq = (const float*)d_in[1];
    const float* bq = (const float*)d_in[2];
    const float* Wk = (const float*)d_in[3];
    const float* bk = (const float*)d_in[4];
    const float* Wv = (const float*)d_in[5];
    const float* bv = (const float*)d_in[6];
    const float* Wo = (const float*)d_in[7];
    const float* bo = (const float*)d_in[8];
    float* out = (float*)d_out;

    char* ws = (char*)d_ws;
    unsigned short* zb   = (unsigned short*)(ws);                        // 16 MB
    unsigned short* ctxb = (unsigned short*)(ws);                        // 16 MB (reuse)
    unsigned short* wqkv = (unsigned short*)(ws + (16ull << 20));        //  6 MB
    unsigned short* wob  = (unsigned short*)(ws + (22ull << 20));        //  2 MB
    float*          biasf= (float*)(ws + (24ull << 20));                 // 12 KB
    unsigned short* qb   = (unsigned short*)(ws + (25ull << 20));        // 16 MB
    unsigned short* kb   = (unsigned short*)(ws + (41ull << 20));        // 16 MB
    unsigned short* vtb  = (unsigned short*)(ws + (57ull << 20));        // 16 MB -> 73 MB total

    k_convert<<<8192, 256, 0, stream>>>(z, Wq, Wk, Wv, Wo, bq, bk, bv, zb, wqkv, wob, biasf);
    k_gemm_qkv<<<64 * 24, 256, 0, stream>>>(zb, wqkv, biasf, qb, kb, vtb);
    k_attn<<<NBH * 8, 512, 0, stream>>>(qb, kb, vtb, ctxb);
    k_gemm_out<<<64 * 8, 256, 0, stream>>>(ctxb, wob, bo, out);
}

// Round 10
// 214.239 us; speedup vs baseline: 1.1169x; 1.0425x over previous
//
#include <hip/hip_runtime.h>
#include <stdint.h>

#define D_MODEL 1024
#define NHEAD 16
#define DKH 64
#define BATCH 4
#define SEQ 2048
#define M_ROWS (BATCH*SEQ)   // 8192
#define NBH (BATCH*NHEAD)    // 64

typedef float f32x4 __attribute__((ext_vector_type(4)));
typedef float f32x16 __attribute__((ext_vector_type(16)));
typedef __bf16 bf16x8 __attribute__((ext_vector_type(8)));
typedef __bf16 bf16x4v __attribute__((ext_vector_type(4)));
typedef short short4v __attribute__((ext_vector_type(4)));
typedef unsigned short ushort4v __attribute__((ext_vector_type(4)));
typedef unsigned short ushort8v __attribute__((ext_vector_type(8)));
typedef unsigned int uint2v __attribute__((ext_vector_type(2)));

__device__ __forceinline__ unsigned short f2bf(float x) {
    __bf16 b = (__bf16)x;                      // hardware v_cvt (RNE)
    return __builtin_bit_cast(unsigned short, b);
}

#define GLL(gsrc, ldst) \
    __builtin_amdgcn_global_load_lds((const __attribute__((address_space(1))) void*)(gsrc), \
                                     (__attribute__((address_space(3))) void*)(ldst), 16, 0, 0)

// ---------------------------------------------------------------------------
// Fragment-order layouts (zero-conflict, zero-swizzle GEMM operands):
//   A-frag tile (BM=256 x BK=64): [mtile][kt][half][mfrag(8)][kk(2)][lane(64)][e(8)]
//     row = mtile*256 + half*128 + mfrag*16 + (lane&15)
//     k   = kt*64 + kk*32 + (lane>>4)*8 + e          tile = 16384 elems (32KB)
//   B-frag tile (BN=128 x BK=64): [ntile][kt][nfrag(8)][kk(2)][lane(64)][e(8)]
//     col = ntile*128 + nfrag*16 + (lane&15), same k   tile = 8192 elems (16KB)
// ---------------------------------------------------------------------------

__device__ __forceinline__ void cvt8store(const float* __restrict__ src,
                                          unsigned short* __restrict__ dst) {
    float4 v0 = *(const float4*)(src);
    float4 v1 = *(const float4*)(src + 4);
    ushort8v o;
    o[0] = f2bf(v0.x); o[1] = f2bf(v0.y); o[2] = f2bf(v0.z); o[3] = f2bf(v0.w);
    o[4] = f2bf(v1.x); o[5] = f2bf(v1.y); o[6] = f2bf(v1.z); o[7] = f2bf(v1.w);
    *(ushort8v*)dst = o;
}

// ---------------------------------------------------------------------------
// Kernel 1: fp32 -> bf16 fragment-order packing
// ---------------------------------------------------------------------------
__global__ __launch_bounds__(256) void k_convert(
    const float* __restrict__ z,  const float* __restrict__ wq,
    const float* __restrict__ wk, const float* __restrict__ wv,
    const float* __restrict__ wo,
    const float* __restrict__ bq, const float* __restrict__ bk,
    const float* __restrict__ bv,
    unsigned short* __restrict__ zf, unsigned short* __restrict__ wqkvf,
    unsigned short* __restrict__ wobf, float* __restrict__ biasf)
{
    int i = blockIdx.x * 256 + threadIdx.x;   // 0 .. 2097151
    if (i < 1048576) {              // zf: 8192x1024 / 8
        int lane = i & 63, rest = i >> 6;
        int kk = rest & 1, mfrag = (rest >> 1) & 7, half = (rest >> 4) & 1;
        int kt = (rest >> 5) & 15, mtile = rest >> 9;
        int row = mtile * 256 + half * 128 + mfrag * 16 + (lane & 15);
        int k = kt * 64 + kk * 32 + (lane >> 4) * 8;
        cvt8store(z + (size_t)row * 1024 + k, zf + (size_t)i * 8);
    }
    int i2 = i - 1048576;
    if (i2 >= 0 && i2 < 393216) {   // wqkvf: 3072x1024 / 8
        int lane = i2 & 63, rest = i2 >> 6;
        int kk = rest & 1, nfrag = (rest >> 1) & 7;
        int kt = (rest >> 4) & 15, ntile = rest >> 8;
        int n = ntile * 128 + nfrag * 16 + (lane & 15);
        int k = kt * 64 + kk * 32 + (lane >> 4) * 8;
        const float* W = (n < 1024) ? wq : ((n < 2048) ? wk : wv);
        cvt8store(W + (size_t)(n & 1023) * 1024 + k, wqkvf + (size_t)i2 * 8);
    }
    int i3 = i2 - 393216;
    if (i3 >= 0 && i3 < 131072) {   // wobf: 1024x1024 / 8
        int lane = i3 & 63, rest = i3 >> 6;
        int kk = rest & 1, nfrag = (rest >> 1) & 7;
        int kt = (rest >> 4) & 15, ntile = rest >> 8;
        int n = ntile * 128 + nfrag * 16 + (lane & 15);
        int k = kt * 64 + kk * 32 + (lane >> 4) * 8;
        cvt8store(wo + (size_t)n * 1024 + k, wobf + (size_t)i3 * 8);
    }
    if (i < 1024) {
        biasf[i]        = bq[i];
        biasf[1024 + i] = bk[i];
        biasf[2048 + i] = bv[i];
    }
}

// ---------------------------------------------------------------------------
// Shared GEMM machinery: 256x128 tile, BK=64, 8 waves (2m x 4n), 3-buffer
// LDS rotation (144KB), counted vmcnt(6) (next-next tile's 6 GLLs stay in
// flight across the barrier), fragment-linear LDS (no conflicts, no addr math)
// ---------------------------------------------------------------------------
__device__ __forceinline__ void g_stage(const unsigned short* __restrict__ as_,
                                        const unsigned short* __restrict__ bs_,
                                        unsigned short* la, unsigned short* lb,
                                        int wid, int lane)
{
#pragma unroll
    for (int g = 0; g < 4; ++g)
        GLL(as_ + (wid + 8 * g) * 512 + lane * 8, la + (wid + 8 * g) * 512);
#pragma unroll
    for (int g = 0; g < 2; ++g)
        GLL(bs_ + (wid + 8 * g) * 512 + lane * 8, lb + (wid + 8 * g) * 512);
}

#define GEMM_KLOOP(Abase, Bbase)                                                      \
    g_stage(Abase, Bbase, &ldsA[0][0], &ldsB[0][0], wid, lane);                       \
    g_stage(Abase + 16384, Bbase + 8192, &ldsA[1][0], &ldsB[1][0], wid, lane);        \
    asm volatile("s_waitcnt vmcnt(6)" ::: "memory");                                  \
    __builtin_amdgcn_s_barrier();                                                     \
    for (int t = 0; t < 16; ++t) {                                                    \
        int buf = t % 3;                                                              \
        if (t + 2 < 16)                                                               \
            g_stage(Abase + (size_t)(t + 2) * 16384, Bbase + (size_t)(t + 2) * 8192,  \
                    &ldsA[(t + 2) % 3][0], &ldsB[(t + 2) % 3][0], wid, lane);         \
        const unsigned short* A = &ldsA[buf][0];                                      \
        const unsigned short* B = &ldsB[buf][0];                                      \
        bf16x8 b00 = *(const bf16x8*)(B + ((wn * 2 + 0) * 2 + 0) * 512 + lane * 8);   \
        bf16x8 b01 = *(const bf16x8*)(B + ((wn * 2 + 0) * 2 + 1) * 512 + lane * 8);   \
        bf16x8 b10 = *(const bf16x8*)(B + ((wn * 2 + 1) * 2 + 0) * 512 + lane * 8);   \
        bf16x8 b11 = *(const bf16x8*)(B + ((wn * 2 + 1) * 2 + 1) * 512 + lane * 8);   \
        _Pragma("unroll")                                                             \
        for (int ii = 0; ii < 8; ++ii) {                                              \
            bf16x8 a0 = *(const bf16x8*)(A + ((wm * 8 + ii) * 2 + 0) * 512 + lane * 8); \
            bf16x8 a1 = *(const bf16x8*)(A + ((wm * 8 + ii) * 2 + 1) * 512 + lane * 8); \
            acc[ii][0] = __builtin_amdgcn_mfma_f32_16x16x32_bf16(a0, b00, acc[ii][0], 0, 0, 0); \
            acc[ii][0] = __builtin_amdgcn_mfma_f32_16x16x32_bf16(a1, b01, acc[ii][0], 0, 0, 0); \
            acc[ii][1] = __builtin_amdgcn_mfma_f32_16x16x32_bf16(a0, b10, acc[ii][1], 0, 0, 0); \
            acc[ii][1] = __builtin_amdgcn_mfma_f32_16x16x32_bf16(a1, b11, acc[ii][1], 0, 0, 0); \
        }                                                                             \
        if (t < 14)       { asm volatile("s_waitcnt vmcnt(6)" ::: "memory"); }        \
        else if (t == 14) { asm volatile("s_waitcnt vmcnt(0)" ::: "memory"); }        \
        if (t < 15) { __builtin_amdgcn_sched_barrier(0); __builtin_amdgcn_s_barrier(); } \
    }

// ---------------------------------------------------------------------------
// Kernel 2: QKV projection. Epilogue: Q row-major [bh][s][dk] (pre-scaled by
// log2(e)/8), K/V scattered into the attention kernel's fragment order.
// ---------------------------------------------------------------------------
__global__ __launch_bounds__(512) void k_gemm_qkv(
    const unsigned short* __restrict__ Af,   // zfrag
    const unsigned short* __restrict__ Bf,   // wqkvfrag
    const float* __restrict__ biasf,
    unsigned short* __restrict__ qb, unsigned short* __restrict__ kfrag,
    unsigned short* __restrict__ vfrag)
{
    __shared__ unsigned short ldsA[3][16384];
    __shared__ unsigned short ldsB[3][8192];

    int bid = blockIdx.x;
    int wg = (bid & 7) * 96 + (bid >> 3);    // 768 blocks, XCD-contiguous
    int tn = wg % 24, tm = wg / 24;
    int tid = threadIdx.x, wid = tid >> 6, lane = tid & 63;
    int wm = wid >> 2, wn = wid & 3;

    const unsigned short* Abase = Af + (size_t)tm * 16 * 16384;
    const unsigned short* Bbase = Bf + (size_t)tn * 16 * 8192;

    f32x4 acc[8][2] = {};
    GEMM_KLOOP(Abase, Bbase)

    const float QSC = 0.18033688011112042f;  // log2(e) / sqrt(64)
    int t3 = tn >> 3;  // 0=Q 1=K 2=V
#pragma unroll
    for (int j = 0; j < 2; ++j) {
        int col = tn * 128 + wn * 32 + j * 16 + (lane & 15);
        float bias = biasf[col];
        int d = col & 1023, h = d >> 6, dk = d & 63;
#pragma unroll
        for (int i = 0; i < 8; ++i) {
#pragma unroll
            for (int r = 0; r < 4; ++r) {
                int row = tm * 256 + wm * 128 + i * 16 + (lane >> 4) * 4 + r;
                float v = acc[i][j][r] + bias;
                if (t3 == 0) v *= QSC;
                unsigned short bv16 = f2bf(v);
                int b_ = row >> 11, s_ = row & 2047;
                int bh = b_ * NHEAD + h;
                if (t3 == 0) {
                    qb[((size_t)bh * SEQ + s_) * DKH + dk] = bv16;
                } else if (t3 == 1) {
                    int kvblk = s_ >> 6, r64 = s_ & 63;
                    int t32 = r64 >> 5, l5 = r64 & 31;
                    int ds = dk >> 4, hi2 = (dk >> 3) & 1, e = dk & 7;
                    kfrag[((size_t)(bh * 32 + kvblk)) * 4096 +
                          (t32 * 4 + ds) * 512 + (hi2 * 32 + l5) * 8 + e] = bv16;
                } else {
                    int kvblk = s_ >> 6, kv64 = s_ & 63;
                    int ks = kv64 >> 3, hi2 = (kv64 >> 2) & 1, e = kv64 & 3;
                    int vt = dk >> 5, l5 = dk & 31;
                    vfrag[((size_t)(bh * 32 + kvblk)) * 4096 +
                          (vt * 8 + ks) * 256 + (hi2 * 32 + l5) * 4 + e] = bv16;
                }
            }
        }
    }
}

// ---------------------------------------------------------------------------
// Kernel 3: flash attention (unchanged R9 two-tile pipeline), epilogue now
// scatters ctx into GEMM-A fragment order for k_gemm_out.
// ---------------------------------------------------------------------------
#define ATTN_STEP(LDSK, LDSV, WPREV, WCUR, DO_PV)                                   \
    {                                                                               \
        f32x16 st0 = {}, st1 = {};                                                  \
        __builtin_amdgcn_s_setprio(1);                                              \
        _Pragma("unroll")                                                           \
        for (int ds = 0; ds < 4; ++ds) {                                            \
            bf16x8 kf0 = *(const bf16x8*)(&(LDSK)[(ds) * 512 + lane * 8]);          \
            bf16x8 kf1 = *(const bf16x8*)(&(LDSK)[(4 + ds) * 512 + lane * 8]);      \
            st0 = __builtin_amdgcn_mfma_f32_32x32x16_bf16(kf0, aq[ds], st0, 0, 0, 0); \
            st1 = __builtin_amdgcn_mfma_f32_32x32x16_bf16(kf1, aq[ds], st1, 0, 0, 0); \
            if (DO_PV) {                                                            \
                short4v vf0 = *(const short4v*)(&(LDSV)[(2 * ds) * 256 + lane * 4]);        \
                short4v vf1 = *(const short4v*)(&(LDSV)[(8 + 2 * ds) * 256 + lane * 4]);    \
                oa0 = __builtin_amdgcn_mfma_f32_32x32x8bf16_1k(vf0, WPREV[2 * ds], oa0, 0, 0, 0); \
                oa1 = __builtin_amdgcn_mfma_f32_32x32x8bf16_1k(vf1, WPREV[2 * ds], oa1, 0, 0, 0); \
                short4v vf2 = *(const short4v*)(&(LDSV)[(2 * ds + 1) * 256 + lane * 4]);    \
                short4v vf3 = *(const short4v*)(&(LDSV)[(8 + 2 * ds + 1) * 256 + lane * 4]);\
                oa0 = __builtin_amdgcn_mfma_f32_32x32x8bf16_1k(vf2, WPREV[2 * ds + 1], oa0, 0, 0, 0); \
                oa1 = __builtin_amdgcn_mfma_f32_32x32x8bf16_1k(vf3, WPREV[2 * ds + 1], oa1, 0, 0, 0); \
            }                                                                       \
        }                                                                           \
        __builtin_amdgcn_s_setprio(0);                                              \
        _Pragma("unroll")                                                           \
        for (int ks = 0; ks < 4; ++ks) {                                            \
            {                                                                       \
                float p0 = __builtin_amdgcn_exp2f(st0[4 * ks + 0]);                 \
                float p1 = __builtin_amdgcn_exp2f(st0[4 * ks + 1]);                 \
                float p2 = __builtin_amdgcn_exp2f(st0[4 * ks + 2]);                 \
                float p3 = __builtin_amdgcn_exp2f(st0[4 * ks + 3]);                 \
                lsum += (p0 + p1) + (p2 + p3);                                      \
                bf16x4v pb;                                                         \
                pb[0] = (__bf16)p0; pb[1] = (__bf16)p1; pb[2] = (__bf16)p2; pb[3] = (__bf16)p3; \
                WCUR[ks] = __builtin_bit_cast(short4v, pb);                         \
            }                                                                       \
            {                                                                       \
                float p0 = __builtin_amdgcn_exp2f(st1[4 * ks + 0]);                 \
                float p1 = __builtin_amdgcn_exp2f(st1[4 * ks + 1]);                 \
                float p2 = __builtin_amdgcn_exp2f(st1[4 * ks + 2]);                 \
                float p3 = __builtin_amdgcn_exp2f(st1[4 * ks + 3]);                 \
                lsum += (p0 + p1) + (p2 + p3);                                      \
                bf16x4v pb;                                                         \
                pb[0] = (__bf16)p0; pb[1] = (__bf16)p1; pb[2] = (__bf16)p2; pb[3] = (__bf16)p3; \
                WCUR[4 + ks] = __builtin_bit_cast(short4v, pb);                     \
            }                                                                       \
        }                                                                           \
    }

#define DRAIN_BARRIER()                                         \
    asm volatile("s_waitcnt vmcnt(0)" ::: "memory");            \
    __builtin_amdgcn_sched_barrier(0);                          \
    __builtin_amdgcn_s_barrier();

__global__ __launch_bounds__(512) void k_attn(
    const unsigned short* __restrict__ qg,
    const unsigned short* __restrict__ kb,
    const unsigned short* __restrict__ vtb,
    unsigned short* __restrict__ ctxf)
{
    __shared__ unsigned short lds_k[2][4096];
    __shared__ unsigned short lds_v[2][4096];

    int bid = blockIdx.x;
    int x = bid & 7, li = bid >> 3;
    int bh = x * 8 + (li >> 3);
    int qt = li & 7;

    int tid = threadIdx.x, wid = tid >> 6, lane = tid & 63;
    int lq = lane & 31, hi = lane >> 5;

    bf16x8 aq[4];
    {
        const unsigned short* qp = qg + ((size_t)bh * SEQ + qt * 256 + wid * 32 + lq) * DKH + hi * 8;
#pragma unroll
        for (int d = 0; d < 4; ++d) aq[d] = *(const bf16x8*)(qp + d * 16);
    }

    float lsum = 0.f;
    f32x16 oa0 = {};
    f32x16 oa1 = {};
    short4v wA[8], wB[8];

    const unsigned short* kbase = kb  + (size_t)bh * 32 * 4096;
    const unsigned short* vbase = vtb + (size_t)bh * 32 * 4096;
    int so = wid * 512 + lane * 8;
    unsigned short* ldk0 = &lds_k[0][wid * 512];
    unsigned short* ldk1 = &lds_k[1][wid * 512];
    unsigned short* ldv0 = &lds_v[0][wid * 512];
    unsigned short* ldv1 = &lds_v[1][wid * 512];

    GLL(kbase + so, ldk0);
    DRAIN_BARRIER();

    GLL(kbase + 4096 + so, ldk1);
    GLL(vbase + so, ldv0);
    ATTN_STEP(lds_k[0], lds_v[0], wB, wA, false);
    DRAIN_BARRIER();

    for (int t = 1; t < 31; t += 2) {
        GLL(kbase + (size_t)(t + 1) * 4096 + so, ldk0);
        GLL(vbase + (size_t)t * 4096 + so, ldv1);
        ATTN_STEP(lds_k[1], lds_v[0], wA, wB, true);
        DRAIN_BARRIER();
        if (t + 2 < 32) GLL(kbase + (size_t)(t + 2) * 4096 + so, ldk1);
        GLL(vbase + (size_t)(t + 1) * 4096 + so, ldv0);
        ATTN_STEP(lds_k[0], lds_v[1], wB, wA, true);
        DRAIN_BARRIER();
    }

    GLL(vbase + (size_t)31 * 4096 + so, ldv1);
    ATTN_STEP(lds_k[1], lds_v[0], wA, wB, true);
    DRAIN_BARRIER();

    __builtin_amdgcn_s_setprio(1);
#pragma unroll
    for (int ks = 0; ks < 8; ++ks) {
        short4v vf0 = *(const short4v*)(&lds_v[1][(ks) * 256 + lane * 4]);
        short4v vf1 = *(const short4v*)(&lds_v[1][(8 + ks) * 256 + lane * 4]);
        oa0 = __builtin_amdgcn_mfma_f32_32x32x8bf16_1k(vf0, wB[ks], oa0, 0, 0, 0);
        oa1 = __builtin_amdgcn_mfma_f32_32x32x8bf16_1k(vf1, wB[ks], oa1, 0, 0, 0);
    }
    __builtin_amdgcn_s_setprio(0);

    // ---- epilogue: scatter ctx into GEMM-A fragment order ----
    // ctx row = b*2048+s, k = h*64+d; d = T*32 + 8m + 4hi + r
    // -> kt = h, kk = T, kg = m, e = 4hi + r
    int b_ = bh >> 4, h = bh & 15;
    lsum += __shfl_xor(lsum, 32);
    float inv = 1.0f / lsum;
    int s_ = qt * 256 + wid * 32 + lq;
    int row = b_ * 2048 + s_;
    int mtile = row >> 8, half = (row >> 7) & 1, mfrag = (row >> 4) & 7, lrow = row & 15;
    unsigned short* cb = ctxf + (size_t)((mtile * 16 + h) * 2 + half) * 8192
                              + mfrag * 1024 + lrow * 8 + 4 * hi;
#pragma unroll
    for (int m = 0; m < 4; ++m) {
        ushort4v s0, s1;
        s0[0] = f2bf(oa0[4 * m + 0] * inv); s0[1] = f2bf(oa0[4 * m + 1] * inv);
        s0[2] = f2bf(oa0[4 * m + 2] * inv); s0[3] = f2bf(oa0[4 * m + 3] * inv);
        *(ushort4v*)(cb + m * 128) = s0;                 // kk=0 (d<32)
        s1[0] = f2bf(oa1[4 * m + 0] * inv); s1[1] = f2bf(oa1[4 * m + 1] * inv);
        s1[2] = f2bf(oa1[4 * m + 2] * inv); s1[3] = f2bf(oa1[4 * m + 3] * inv);
        *(ushort4v*)(cb + 512 + m * 128) = s1;           // kk=1 (d>=32)
    }
}

// ---------------------------------------------------------------------------
// Kernel 4: output projection, same 256x128 counted-vmcnt GEMM, fp32 out
// ---------------------------------------------------------------------------
__global__ __launch_bounds__(512) void k_gemm_out(
    const unsigned short* __restrict__ Af,   // ctxfrag
    const unsigned short* __restrict__ Bf,   // wobfrag
    const float* __restrict__ bo,
    float* __restrict__ out)
{
    __shared__ unsigned short ldsA[3][16384];
    __shared__ unsigned short ldsB[3][8192];

    int bid = blockIdx.x;
    int wg = (bid & 7) * 32 + (bid >> 3);    // 256 blocks
    int tn = wg % 8, tm = wg / 8;
    int tid = threadIdx.x, wid = tid >> 6, lane = tid & 63;
    int wm = wid >> 2, wn = wid & 3;

    const unsigned short* Abase = Af + (size_t)tm * 16 * 16384;
    const unsigned short* Bbase = Bf + (size_t)tn * 16 * 8192;

    f32x4 acc[8][2] = {};
    GEMM_KLOOP(Abase, Bbase)

#pragma unroll
    for (int j = 0; j < 2; ++j) {
        int col = tn * 128 + wn * 32 + j * 16 + (lane & 15);
        float bias = bo[col];
#pragma unroll
        for (int i = 0; i < 8; ++i) {
#pragma unroll
            for (int r = 0; r < 4; ++r) {
                int row = tm * 256 + wm * 128 + i * 16 + (lane >> 4) * 4 + r;
                out[(size_t)row * 1024 + col] = acc[i][j][r] + bias;
            }
        }
    }
}

// ---------------------------------------------------------------------------
extern "C" void kernel_launch(void* const* d_in, const int* in_sizes, int n_in,
                              void* d_out, int out_size, void* d_ws, size_t ws_size,
                              hipStream_t stream)
{
    const float* z  = (const float*)d_in[0];
    const float* Wq = (const float*)d_in[1];
    const float* bq = (const float*)d_in[2];
    const float* Wk = (const float*)d_in[3];
    const float* bk = (const float*)d_in[4];
    const float* Wv = (const float*)d_in[5];
    const float* bv = (const float*)d_in[6];
    const float* Wo = (const float*)d_in[7];
    const float* bo = (const float*)d_in[8];
    float* out = (float*)d_out;

    char* ws = (char*)d_ws;
    unsigned short* zf    = (unsigned short*)(ws);                        // 16 MB
    unsigned short* ctxf  = (unsigned short*)(ws);                        // 16 MB (reuse; zf dead after qkv)
    unsigned short* wqkvf = (unsigned short*)(ws + (16ull << 20));        //  6 MB
    unsigned short* wobf  = (unsigned short*)(ws + (22ull << 20));        //  2 MB
    float*          biasf = (float*)(ws + (24ull << 20));                 // 12 KB
    unsigned short* qb    = (unsigned short*)(ws + (25ull << 20));        // 16 MB
    unsigned short* kfrag = (unsigned short*)(ws + (41ull << 20));        // 16 MB
    unsigned short* vfrag = (unsigned short*)(ws + (57ull << 20));        // 16 MB -> 73 MB total

    k_convert<<<8192, 256, 0, stream>>>(z, Wq, Wk, Wv, Wo, bq, bk, bv, zf, wqkvf, wobf, biasf);
    k_gemm_qkv<<<768, 512, 0, stream>>>(zf, wqkvf, biasf, qb, kfrag, vfrag);
    k_attn<<<NBH * 8, 512, 0, stream>>>(qb, kfrag, vfrag, ctxf);
    k_gemm_out<<<256, 512, 0, stream>>>(ctxf, wobf, bo, out);
}